// Round 1
// baseline (27949.686 us; speedup 1.0000x reference)
//
#include <hip/hip_runtime.h>
#include <hip/hip_bf16.h>

// mLSTM: L=512, N=32, H_IN=H=1024, 2 layers.
// Inputs: 0 inputs, 1 Wmx0, 2 Wmh0, 3 bmx0, 4 bmh0, 5 Wgx0, 6 Wgm0, 7 bg0,
//         8 Wmx1, 9 Wmh1, 10 bmx1, 11 bmh1, 12 Wgx1, 13 Wgm1, 14 bg1
// Output: ys (512*32*1024) | hs (2*32*1024) | cs (2*32*1024)  -- fp32

typedef unsigned short u16;
typedef __attribute__((ext_vector_type(8))) short bf16x8;
typedef __attribute__((ext_vector_type(4))) float f32x4;

#define LSEQ 512
#define NB   32
#define HD   1024
#define G4   4096
#define YSZ  (LSEQ*NB*HD)
#define NH32 (NB*HD)

__device__ __forceinline__ float b2f(u16 u) {
    unsigned int i = ((unsigned int)u) << 16;
    float f; __builtin_memcpy(&f, &i, 4); return f;
}
__device__ __forceinline__ u16 f2b(float f) {
    unsigned int x; __builtin_memcpy(&x, &f, 4);
    unsigned int r = (x + 0x7fffu + ((x >> 16) & 1u)) >> 16;
    return (u16)r;
}

// ---------------- conversion / packing ----------------
__global__ void k_cvt(const float* __restrict__ s, u16* __restrict__ d, long n) {
    long i = (long)blockIdx.x * blockDim.x + threadIdx.x;
    long stride = (long)gridDim.x * blockDim.x;
    for (; i < n; i += stride) d[i] = f2b(s[i]);
}

// pack [Wgx | Wgm] -> Wg[4096][2048] bf16
__global__ void k_pack_wg(const float* __restrict__ gx, const float* __restrict__ gm,
                          u16* __restrict__ d) {
    long n = (long)G4 * 2048;
    long i = (long)blockIdx.x * blockDim.x + threadIdx.x;
    long stride = (long)gridDim.x * blockDim.x;
    for (; i < n; i += stride) {
        long r = i >> 11; int k = (int)(i & 2047);
        float v = (k < 1024) ? gx[r * 1024 + k] : gm[r * 1024 + (k - 1024)];
        d[i] = f2b(v);
    }
}

// ---------------- big GEMM: Out = bf16(X @ W^T + bias), M x 1024, K=1024 ----------------
// X: [M][1024] bf16 row-major; W: [1024][1024] bf16 row-major (N x K)
__global__ __launch_bounds__(256) void k_gemm_A(
    const u16* __restrict__ X, const u16* __restrict__ W,
    const float* __restrict__ bias, u16* __restrict__ Out, int M)
{
    __shared__ u16 As[128][40];  // +8 pad: 80B row stride -> 2-way (free) conflicts
    __shared__ u16 Bs[128][40];
    int bm = blockIdx.y, bn = blockIdx.x;
    int tid = threadIdx.x;
    int w = tid >> 6, lane = tid & 63;
    int wm = w >> 1, wn = w & 1;
    int l16 = lane & 15, lk = lane >> 4;

    f32x4 acc[4][4];
    #pragma unroll
    for (int i = 0; i < 4; ++i)
        #pragma unroll
        for (int j = 0; j < 4; ++j) acc[i][j] = (f32x4){0.f, 0.f, 0.f, 0.f};

    for (int kt = 0; kt < 32; ++kt) {
        __syncthreads();
        #pragma unroll
        for (int c = 0; c < 2; ++c) {
            int cid = tid + c * 256;
            int rrow = cid >> 2, kc = (cid & 3) * 8;
            *(bf16x8*)(&As[rrow][kc]) =
                *(const bf16x8*)(X + (long)(bm * 128 + rrow) * HD + kt * 32 + kc);
            *(bf16x8*)(&Bs[rrow][kc]) =
                *(const bf16x8*)(W + (long)(bn * 128 + rrow) * HD + kt * 32 + kc);
        }
        __syncthreads();
        bf16x8 af[4], bfr[4];
        #pragma unroll
        for (int mt = 0; mt < 4; ++mt)
            af[mt] = *(const bf16x8*)(&As[wm * 64 + mt * 16 + l16][lk * 8]);
        #pragma unroll
        for (int nt = 0; nt < 4; ++nt)
            bfr[nt] = *(const bf16x8*)(&Bs[wn * 64 + nt * 16 + l16][lk * 8]);
        #pragma unroll
        for (int mt = 0; mt < 4; ++mt)
            #pragma unroll
            for (int nt = 0; nt < 4; ++nt)
                acc[mt][nt] = __builtin_amdgcn_mfma_f32_16x16x32_bf16(
                    af[mt], bfr[nt], acc[mt][nt], 0, 0, 0);
    }
    #pragma unroll
    for (int mt = 0; mt < 4; ++mt)
        #pragma unroll
        for (int nt = 0; nt < 4; ++nt) {
            int colg = bn * 128 + wn * 64 + nt * 16 + l16;
            float bv = bias[colg];
            #pragma unroll
            for (int r = 0; r < 4; ++r) {
                int rowg = bm * 128 + wm * 64 + mt * 16 + lk * 4 + r;
                Out[(long)rowg * HD + colg] = f2b(acc[mt][nt][r] + bv);
            }
        }
}

// ---------------- per-step: m = A_t * (h @ Wmh^T + bmh) ----------------
// grid 32 blocks x 256 thr; block b owns cols [32b, 32b+32)
__global__ __launch_bounds__(256) void k_step_m(
    const u16* __restrict__ h,    // [32][1024] bf16
    const u16* __restrict__ Wmh,  // [1024][1024] bf16 (N x K)
    const float* __restrict__ bmh,
    const u16* __restrict__ At,   // [32][1024] bf16 (x@Wmx^T + bmx)
    u16* __restrict__ m_out)      // [32][1024] bf16
{
    int b = blockIdx.x;
    int tid = threadIdx.x;
    int w = tid >> 6, lane = tid & 63;
    int wm = w >> 1, wn = w & 1;
    int l16 = lane & 15, lk = lane >> 4;
    int arow = wm * 16 + l16;
    int col = b * 32 + wn * 16 + l16;

    const bf16x8* hp = (const bf16x8*)(h + (long)arow * HD);
    const bf16x8* wp = (const bf16x8*)(Wmh + (long)col * HD);
    f32x4 acc = (f32x4){0.f, 0.f, 0.f, 0.f};
    #pragma unroll 8
    for (int kt = 0; kt < 32; ++kt) {
        bf16x8 a = hp[kt * 4 + lk];
        bf16x8 bb = wp[kt * 4 + lk];
        acc = __builtin_amdgcn_mfma_f32_16x16x32_bf16(a, bb, acc, 0, 0, 0);
    }
    float bc = bmh[col];
    #pragma unroll
    for (int r = 0; r < 4; ++r) {
        int orow = wm * 16 + lk * 4 + r;
        float a_t = b2f(At[(long)orow * HD + col]);
        float mval = a_t * (acc[r] + bc);
        m_out[(long)orow * HD + col] = f2b(mval);
    }
}

// ---------------- per-step: g = [x;m] @ Wg^T + bg; gates; state update ----------------
// grid 128 blocks x 256 thr; block b owns h-cols [8b, 8b+8)
__global__ __launch_bounds__(256) void k_step_g(
    const u16* __restrict__ xt,   // [32][1024] bf16 (x_t)
    const u16* __restrict__ mt,   // [32][1024] bf16 (m_t)
    const u16* __restrict__ Wg,   // [4096][2048] bf16 packed [Wgx|Wgm]
    const float* __restrict__ bg, // [4096]
    float* __restrict__ cbuf,     // [32][1024] fp32 persistent c
    u16* __restrict__ h_exch,     // [32][1024] bf16 h out
    float* __restrict__ ys_f32,   // nullable (layer 1: d_out + t*NH32)
    u16* __restrict__ ys_b16,     // nullable (layer 0: Yb + t*NH32)
    float* __restrict__ tail_h,   // nullable (t==511)
    float* __restrict__ tail_c)   // nullable (t==511)
{
    __shared__ float gt[2][32][16];
    int b = blockIdx.x;
    int tid = threadIdx.x;
    int w = tid >> 6, lane = tid & 63;
    int wm = w >> 1, wn = w & 1;
    int l16 = lane & 15, lk = lane >> 4;
    int arow = wm * 16 + l16;
    // g-row this lane's B-fragment belongs to (i,f for wn=0; z,o for wn=1)
    int grow = (l16 < 8) ? (wn * 2048 + b * 8 + l16)
                         : (wn * 2048 + 1024 + b * 8 + (l16 - 8));

    const bf16x8* ap_x = (const bf16x8*)(xt + (long)arow * HD);
    const bf16x8* ap_m = (const bf16x8*)(mt + (long)arow * HD);
    const bf16x8* wp = (const bf16x8*)(Wg + (long)grow * 2048);

    f32x4 acc = (f32x4){0.f, 0.f, 0.f, 0.f};
    #pragma unroll 8
    for (int kt = 0; kt < 32; ++kt) {
        bf16x8 a = ap_x[kt * 4 + lk];
        bf16x8 bb = wp[kt * 4 + lk];
        acc = __builtin_amdgcn_mfma_f32_16x16x32_bf16(a, bb, acc, 0, 0, 0);
    }
    #pragma unroll 8
    for (int kt = 32; kt < 64; ++kt) {
        bf16x8 a = ap_m[(kt - 32) * 4 + lk];
        bf16x8 bb = wp[kt * 4 + lk];
        acc = __builtin_amdgcn_mfma_f32_16x16x32_bf16(a, bb, acc, 0, 0, 0);
    }
    float bgv = bg[grow];
    #pragma unroll
    for (int r = 0; r < 4; ++r) {
        int orow = wm * 16 + lk * 4 + r;
        gt[wn][orow][l16] = acc[r] + bgv;
    }
    __syncthreads();

    int r = tid >> 3, j = tid & 7;
    float ig = gt[0][r][j], fg = gt[0][r][8 + j];
    float zg = gt[1][r][j], og = gt[1][r][8 + j];
    int colh = b * 8 + j;
    float c_old = cbuf[(long)r * HD + colh];
    float si = 1.f / (1.f + expf(-ig));
    float sf = 1.f / (1.f + expf(-fg));
    float so = 1.f / (1.f + expf(-og));
    float tz = tanhf(zg);
    float cn = sf * c_old + si * tz;
    float hn = so * tanhf(cn);
    cbuf[(long)r * HD + colh] = cn;
    h_exch[(long)r * HD + colh] = f2b(hn);
    if (ys_f32) ys_f32[(long)r * HD + colh] = hn;
    if (ys_b16) ys_b16[(long)r * HD + colh] = f2b(hn);
    if (tail_h) { tail_h[(long)r * HD + colh] = hn; tail_c[(long)r * HD + colh] = cn; }
}

extern "C" void kernel_launch(void* const* d_in, const int* in_sizes, int n_in,
                              void* d_out, int out_size, void* d_ws, size_t ws_size,
                              hipStream_t stream) {
    (void)in_sizes; (void)n_in; (void)out_size; (void)ws_size;
    const float* inputs = (const float*)d_in[0];
    const float* Wmx[2] = {(const float*)d_in[1], (const float*)d_in[8]};
    const float* Wmh[2] = {(const float*)d_in[2], (const float*)d_in[9]};
    const float* bmx[2] = {(const float*)d_in[3], (const float*)d_in[10]};
    const float* bmh[2] = {(const float*)d_in[4], (const float*)d_in[11]};
    const float* Wgx[2] = {(const float*)d_in[5], (const float*)d_in[12]};
    const float* Wgm[2] = {(const float*)d_in[6], (const float*)d_in[13]};
    const float* bg[2]  = {(const float*)d_in[7], (const float*)d_in[14]};
    float* out = (float*)d_out;

    // workspace layout (bytes)
    char* ws = (char*)d_ws;
    const long MB = 1024L * 1024L;
    u16* Wmxb[2] = {(u16*)(ws + 0 * MB), (u16*)(ws + 2 * MB)};
    u16* Wmhb[2] = {(u16*)(ws + 4 * MB), (u16*)(ws + 6 * MB)};
    u16* Wgb[2]  = {(u16*)(ws + 8 * MB), (u16*)(ws + 24 * MB)};
    u16* Xb      = (u16*)(ws + 40 * MB);   // 32MB  bf16 inputs
    u16* Yb      = (u16*)(ws + 72 * MB);   // 32MB  bf16 layer-0 outputs
    u16* Ab      = (u16*)(ws + 104 * MB);  // 32MB  bf16 precomputed m-input
    u16* exch_h  = (u16*)(ws + 136 * MB);          // 64KB
    u16* exch_m  = (u16*)(ws + 136 * MB + 65536);  // 64KB
    float* cbuf  = (float*)(ws + 136 * MB + 131072); // 128KB

    // init state (h0 = c0 = 0)
    hipMemsetAsync(exch_h, 0, NH32 * sizeof(u16), stream);
    hipMemsetAsync(cbuf, 0, NH32 * sizeof(float), stream);

    // conversions
    k_cvt<<<2048, 256, 0, stream>>>(Wmx[0], Wmxb[0], (long)HD * HD);
    k_cvt<<<2048, 256, 0, stream>>>(Wmx[1], Wmxb[1], (long)HD * HD);
    k_cvt<<<2048, 256, 0, stream>>>(Wmh[0], Wmhb[0], (long)HD * HD);
    k_cvt<<<2048, 256, 0, stream>>>(Wmh[1], Wmhb[1], (long)HD * HD);
    k_cvt<<<4096, 256, 0, stream>>>(inputs, Xb, (long)YSZ);
    k_pack_wg<<<4096, 256, 0, stream>>>(Wgx[0], Wgm[0], Wgb[0]);
    k_pack_wg<<<4096, 256, 0, stream>>>(Wgx[1], Wgm[1], Wgb[1]);

    for (int l = 0; l < 2; ++l) {
        const u16* xsrc = l ? Yb : Xb;
        k_gemm_A<<<dim3(8, 128), 256, 0, stream>>>(xsrc, Wmxb[l], bmx[l], Ab, LSEQ * NB);
        for (int t = 0; t < LSEQ; ++t) {
            k_step_m<<<32, 256, 0, stream>>>(exch_h, Wmhb[l], bmh[l],
                                             Ab + (long)t * NH32, exch_m);
            float* ysf = l ? (out + (long)t * NH32) : nullptr;
            u16* ysb = l ? nullptr : (Yb + (long)t * NH32);
            float* th = (t == LSEQ - 1) ? (out + YSZ + (long)l * NH32) : nullptr;
            float* tc = (t == LSEQ - 1) ? (out + YSZ + 2L * NH32 + (long)l * NH32) : nullptr;
            k_step_g<<<128, 256, 0, stream>>>(xsrc + (long)t * NH32, exch_m, Wgb[l],
                                              bg[l], cbuf, exch_h, ysf, ysb, th, tc);
        }
    }
}

// Round 2
// 24523.312 us; speedup vs baseline: 1.1397x; 1.1397x over previous
//
#include <hip/hip_runtime.h>
#include <hip/hip_bf16.h>

// mLSTM persistent-kernel implementation. L=512, N=32, H=1024, 2 layers.
// Out: ys (512*32*1024) | hs (2*32*1024) | cs (2*32*1024), fp32.

typedef unsigned short u16;
typedef unsigned int u32;
typedef __attribute__((ext_vector_type(8))) short bf16x8;
typedef __attribute__((ext_vector_type(4))) float f32x4;

#define LSEQ 512
#define NB   32
#define HD   1024
#define G4   4096
#define YSZ  (LSEQ*NB*HD)
#define NH32 (NB*HD)
#define SEG  64
#define NSEG (LSEQ/SEG)
#define PERSIST_LDS 139264  // 128KB Wgm + 8KB gate-exchange (phase-2); phase-1 uses 64KB

__device__ __forceinline__ float b2f(u16 u) {
    u32 i = ((u32)u) << 16; float f; __builtin_memcpy(&f, &i, 4); return f;
}
__device__ __forceinline__ u16 f2b(float f) {
    u32 x; __builtin_memcpy(&x, &f, 4);
    return (u16)((x + 0x7fffu + ((x >> 16) & 1u)) >> 16);
}
// LDS bank-conflict swizzle for row-major tiles with 2KB/512B row stride
__device__ __forceinline__ int SW(int row, int byte) { return byte ^ ((row & 7) << 4); }

// ---------------- f32 -> bf16 conversion ----------------
__global__ void k_cvt(const float* __restrict__ s, u16* __restrict__ d, long n) {
    long i = (long)blockIdx.x * blockDim.x + threadIdx.x;
    long stride = (long)gridDim.x * blockDim.x;
    for (; i < n; i += stride) d[i] = f2b(s[i]);
}

// ---------------- generic 8-elem loader (f32 converts on the fly) -------
template<typename XT> __device__ __forceinline__ bf16x8 ld8(const XT* p);
template<> __device__ __forceinline__ bf16x8 ld8<u16>(const u16* p) {
    return *(const bf16x8*)p;
}
template<> __device__ __forceinline__ bf16x8 ld8<float>(const float* p) {
    float4 a = *(const float4*)p, b = *(const float4*)(p + 4);
    bf16x8 r;
    r[0]=(short)f2b(a.x); r[1]=(short)f2b(a.y); r[2]=(short)f2b(a.z); r[3]=(short)f2b(a.w);
    r[4]=(short)f2b(b.x); r[5]=(short)f2b(b.y); r[6]=(short)f2b(b.z); r[7]=(short)f2b(b.w);
    return r;
}

// ------- big GEMM: Out[M][ldo-cols] = bf16(X[M][1024] @ W[ncols][1024]^T + bias) -------
template<typename XT>
__global__ __launch_bounds__(256) void k_gemm(
    const XT* __restrict__ X, const u16* __restrict__ W,
    const float* __restrict__ bias, u16* __restrict__ Out, int ldo)
{
    __shared__ u16 As[128][40];
    __shared__ u16 Bs[128][40];
    int bm = blockIdx.y, bn = blockIdx.x;
    int tid = threadIdx.x;
    int w = tid >> 6, lane = tid & 63;
    int wm = w >> 1, wn = w & 1;
    int l16 = lane & 15, lk = lane >> 4;

    f32x4 acc[4][4];
    #pragma unroll
    for (int i = 0; i < 4; ++i)
        #pragma unroll
        for (int j = 0; j < 4; ++j) acc[i][j] = (f32x4){0.f, 0.f, 0.f, 0.f};

    for (int kt = 0; kt < 32; ++kt) {
        __syncthreads();
        #pragma unroll
        for (int c = 0; c < 2; ++c) {
            int cid = tid + c * 256;
            int rrow = cid >> 2, kc = (cid & 3) * 8;
            *(bf16x8*)(&As[rrow][kc]) = ld8<XT>(X + (long)(bm * 128 + rrow) * HD + kt * 32 + kc);
            *(bf16x8*)(&Bs[rrow][kc]) = ld8<u16>(W + (long)(bn * 128 + rrow) * HD + kt * 32 + kc);
        }
        __syncthreads();
        bf16x8 af[4], bfr[4];
        #pragma unroll
        for (int mt = 0; mt < 4; ++mt)
            af[mt] = *(const bf16x8*)(&As[wm * 64 + mt * 16 + l16][lk * 8]);
        #pragma unroll
        for (int nt = 0; nt < 4; ++nt)
            bfr[nt] = *(const bf16x8*)(&Bs[wn * 64 + nt * 16 + l16][lk * 8]);
        #pragma unroll
        for (int mt = 0; mt < 4; ++mt)
            #pragma unroll
            for (int nt = 0; nt < 4; ++nt)
                acc[mt][nt] = __builtin_amdgcn_mfma_f32_16x16x32_bf16(
                    af[mt], bfr[nt], acc[mt][nt], 0, 0, 0);
    }
    #pragma unroll
    for (int mt = 0; mt < 4; ++mt)
        #pragma unroll
        for (int nt = 0; nt < 4; ++nt) {
            int colg = bn * 128 + wn * 64 + nt * 16 + l16;
            float bv = bias[colg];
            #pragma unroll
            for (int r = 0; r < 4; ++r) {
                int rowg = bm * 128 + wm * 64 + mt * 16 + lk * 4 + r;
                Out[(long)rowg * ldo + colg] = f2b(acc[mt][nt][r] + bv);
            }
        }
}

// ---------------- persistent recurrent kernel (one 64-step segment) ----------------
// grid = 96 blocks x 256 thr. Blocks [0,32): phase-1 (m). Blocks [32,96): phase-2 (g/h/c).
// >80KB LDS per block forces 1 block/CU -> all 96 co-resident -> spin barriers safe.
__global__ __launch_bounds__(256) void k_persist(
    const u16* __restrict__ Wmhb, const float* __restrict__ bmh,
    const u16* __restrict__ Wgmb,
    const u16* __restrict__ Ab,    // [512][32][1024] bf16, layer-local index
    const u16* __restrict__ Gxb,   // [SEG][32][4096] bf16, chunk-local index
    u16* exch_h, u16* exch_m,      // [32][1024] bf16 exchange (no __restrict__: must reload each step)
    float* cbuf,                   // [32][1024] f32 persistent c
    u16* __restrict__ yb,          // layer0: Yb base, else null
    float* __restrict__ yf,        // layer1: out base, else null
    float* __restrict__ tail,      // out + YSZ
    int l, int tbc, int tbi,       // layer, counter step base (global), layer-local step base
    u32* cnt_m, u32* cnt_h)
{
    extern __shared__ __align__(16) char lds[];
    const int tid = threadIdx.x;
    const int w = tid >> 6, lane = tid & 63;
    const int l16 = lane & 15, lk = lane >> 4;
    const int wm = w >> 1;
    const int arow = wm * 16 + l16;

    if (blockIdx.x < 32) {
        // ================= phase 1: m = A_t * (h @ Wmh^T + bmh) =================
        const int p = blockIdx.x;
        const int wn = w & 1;
        // stage Wmh rows [32p, 32p+32) once (64KB, swizzled)
        for (int it = 0; it < 16; ++it) {
            int c = tid + it * 256, r = c >> 7, k8 = c & 127;
            bf16x8 v = *(const bf16x8*)(Wmhb + (long)(32 * p + r) * HD + k8 * 8);
            *(bf16x8*)(lds + SW(r, r * 2048 + k8 * 16)) = v;
        }
        const int colg = 32 * p + wn * 16 + l16;
        const float bcol = bmh[colg];
        const int brow = wn * 16 + l16;

        for (int t = 0; t < SEG; ++t) {
            const int gt = tbc + t;
            // prefetch A_t values (static data) before the spin
            const u16* At = Ab + (long)(tbi + t) * NH32;
            u16 atv[4];
            #pragma unroll
            for (int r2 = 0; r2 < 4; ++r2)
                atv[r2] = At[(wm * 16 + lk * 4 + r2) * HD + colg];
            if (tid == 0) {
                while (__hip_atomic_load(cnt_h, __ATOMIC_ACQUIRE, __HIP_MEMORY_SCOPE_AGENT)
                       < 64u * (u32)gt)
                    __builtin_amdgcn_s_sleep(1);
            }
            __syncthreads();
            f32x4 acc = (f32x4){0.f, 0.f, 0.f, 0.f};
            #pragma unroll 8
            for (int kt = 0; kt < 32; ++kt) {
                bf16x8 a = *(const bf16x8*)(exch_h + arow * HD + kt * 32 + lk * 8);
                bf16x8 b = *(const bf16x8*)(lds + SW(brow, brow * 2048 + kt * 64 + lk * 16));
                acc = __builtin_amdgcn_mfma_f32_16x16x32_bf16(a, b, acc, 0, 0, 0);
            }
            #pragma unroll
            for (int r2 = 0; r2 < 4; ++r2) {
                int orow = wm * 16 + lk * 4 + r2;
                exch_m[orow * HD + colg] = f2b(b2f(atv[r2]) * (acc[r2] + bcol));
            }
            __syncthreads();  // drains all waves' m-stores (vmcnt) before release
            if (tid == 0)
                __hip_atomic_fetch_add(cnt_m, 1u, __ATOMIC_RELEASE, __HIP_MEMORY_SCOPE_AGENT);
        }
    } else {
        // ============ phase 2: g = Gx_t + m @ Wgm^T; gates; h,c update ============
        const int q = blockIdx.x - 32;       // owns h-cols [16q, 16q+16)
        const int wg2 = w & 1;               // gates {i,f} vs {z,o}
        float* gtl = (float*)(lds + 131072); // [4][32][16] f32 gate exchange
        // stage Wgm rows (4 gates x 16 cols) once (128KB, swizzled)
        for (int it = 0; it < 32; ++it) {
            int c = tid + it * 256, lr = c >> 7, k8 = c & 127;
            int grow = (lr >> 4) * 1024 + 16 * q + (lr & 15);
            bf16x8 v = *(const bf16x8*)(Wgmb + (long)grow * HD + k8 * 8);
            *(bf16x8*)(lds + SW(lr, lr * 2048 + k8 * 16)) = v;
        }
        const int rr = tid >> 3, j0 = tid & 7;
        const int hc0 = 16 * q + j0, hc1 = hc0 + 8;
        float cr0 = cbuf[rr * HD + hc0];
        float cr1 = cbuf[rr * HD + hc1];
        const int lr0 = 32 * wg2 + l16, lr1 = lr0 + 16;

        for (int t = 0; t < SEG; ++t) {
            const int gt = tbc + t;
            // prefetch Gx (static within launch) before the spin
            const u16* Gx = Gxb + (long)t * NB * G4;
            u16 gxv0[4], gxv1[4];
            #pragma unroll
            for (int r2 = 0; r2 < 4; ++r2) {
                int orow = wm * 16 + lk * 4 + r2;
                gxv0[r2] = Gx[orow * G4 + (2 * wg2) * 1024 + 16 * q + l16];
                gxv1[r2] = Gx[orow * G4 + (2 * wg2 + 1) * 1024 + 16 * q + l16];
            }
            if (tid == 0) {
                while (__hip_atomic_load(cnt_m, __ATOMIC_ACQUIRE, __HIP_MEMORY_SCOPE_AGENT)
                       < 32u * (u32)(gt + 1))
                    __builtin_amdgcn_s_sleep(1);
            }
            __syncthreads();
            f32x4 acc0 = (f32x4){0.f, 0.f, 0.f, 0.f};
            f32x4 acc1 = (f32x4){0.f, 0.f, 0.f, 0.f};
            #pragma unroll 8
            for (int kt = 0; kt < 32; ++kt) {
                bf16x8 a = *(const bf16x8*)(exch_m + arow * HD + kt * 32 + lk * 8);
                bf16x8 b0 = *(const bf16x8*)(lds + SW(lr0, lr0 * 2048 + kt * 64 + lk * 16));
                bf16x8 b1 = *(const bf16x8*)(lds + SW(lr1, lr1 * 2048 + kt * 64 + lk * 16));
                acc0 = __builtin_amdgcn_mfma_f32_16x16x32_bf16(a, b0, acc0, 0, 0, 0);
                acc1 = __builtin_amdgcn_mfma_f32_16x16x32_bf16(a, b1, acc1, 0, 0, 0);
            }
            #pragma unroll
            for (int r2 = 0; r2 < 4; ++r2) {
                int orow = wm * 16 + lk * 4 + r2;
                gtl[((2 * wg2)     * 32 + orow) * 16 + l16] = acc0[r2] + b2f(gxv0[r2]);
                gtl[((2 * wg2 + 1) * 32 + orow) * 16 + l16] = acc1[r2] + b2f(gxv1[r2]);
            }
            __syncthreads();
            float ig0 = gtl[(0 * 32 + rr) * 16 + j0], ig1 = gtl[(0 * 32 + rr) * 16 + j0 + 8];
            float fg0 = gtl[(1 * 32 + rr) * 16 + j0], fg1 = gtl[(1 * 32 + rr) * 16 + j0 + 8];
            float zg0 = gtl[(2 * 32 + rr) * 16 + j0], zg1 = gtl[(2 * 32 + rr) * 16 + j0 + 8];
            float og0 = gtl[(3 * 32 + rr) * 16 + j0], og1 = gtl[(3 * 32 + rr) * 16 + j0 + 8];
            float si0 = 1.f / (1.f + expf(-ig0)), si1 = 1.f / (1.f + expf(-ig1));
            float sf0 = 1.f / (1.f + expf(-fg0)), sf1 = 1.f / (1.f + expf(-fg1));
            float so0 = 1.f / (1.f + expf(-og0)), so1 = 1.f / (1.f + expf(-og1));
            float cn0 = sf0 * cr0 + si0 * tanhf(zg0);
            float cn1 = sf1 * cr1 + si1 * tanhf(zg1);
            float hn0 = so0 * tanhf(cn0);
            float hn1 = so1 * tanhf(cn1);
            cr0 = cn0; cr1 = cn1;
            exch_h[rr * HD + hc0] = f2b(hn0);
            exch_h[rr * HD + hc1] = f2b(hn1);
            long yidx = (long)(tbi + t) * NH32 + rr * HD;
            if (yb) { yb[yidx + hc0] = f2b(hn0); yb[yidx + hc1] = f2b(hn1); }
            else    { yf[yidx + hc0] = hn0;      yf[yidx + hc1] = hn1; }
            if (tbi + t == LSEQ - 1) {
                tail[(long)l * NH32 + rr * HD + hc0] = hn0;
                tail[(long)l * NH32 + rr * HD + hc1] = hn1;
                tail[2L * NH32 + (long)l * NH32 + rr * HD + hc0] = cn0;
                tail[2L * NH32 + (long)l * NH32 + rr * HD + hc1] = cn1;
            }
            __syncthreads();  // drains h/y stores before release
            if (tid == 0)
                __hip_atomic_fetch_add(cnt_h, 1u, __ATOMIC_RELEASE, __HIP_MEMORY_SCOPE_AGENT);
        }
        // save register c for the next segment / layer
        cbuf[rr * HD + hc0] = cr0;
        cbuf[rr * HD + hc1] = cr1;
    }
}

extern "C" void kernel_launch(void* const* d_in, const int* in_sizes, int n_in,
                              void* d_out, int out_size, void* d_ws, size_t ws_size,
                              hipStream_t stream) {
    (void)in_sizes; (void)n_in; (void)out_size; (void)ws_size;
    const float* inputs = (const float*)d_in[0];
    const float* Wmx[2] = {(const float*)d_in[1], (const float*)d_in[8]};
    const float* Wmh[2] = {(const float*)d_in[2], (const float*)d_in[9]};
    const float* bmx[2] = {(const float*)d_in[3], (const float*)d_in[10]};
    const float* bmh[2] = {(const float*)d_in[4], (const float*)d_in[11]};
    const float* Wgx[2] = {(const float*)d_in[5], (const float*)d_in[12]};
    const float* Wgm[2] = {(const float*)d_in[6], (const float*)d_in[13]};
    const float* bg[2]  = {(const float*)d_in[7], (const float*)d_in[14]};
    float* out = (float*)d_out;

    char* ws = (char*)d_ws;
    const long MB = 1024L * 1024L;
    u16* Wmxb[2] = {(u16*)(ws + 0 * MB),  (u16*)(ws + 2 * MB)};
    u16* Wmhb[2] = {(u16*)(ws + 4 * MB),  (u16*)(ws + 6 * MB)};
    u16* Wgxb[2] = {(u16*)(ws + 8 * MB),  (u16*)(ws + 16 * MB)};
    u16* Wgmb[2] = {(u16*)(ws + 24 * MB), (u16*)(ws + 32 * MB)};
    u16* Yb  = (u16*)(ws + 40 * MB);   // 32MB bf16 layer-0 outputs
    u16* Ab  = (u16*)(ws + 72 * MB);   // 32MB bf16 A = x@Wmx+bmx (per layer)
    u16* Gxb = (u16*)(ws + 104 * MB);  // 16MB bf16 Gx chunk = x@Wgx+bg (per segment)
    char* ex = ws + 120 * MB;
    u16* exch_h = (u16*)ex;
    u16* exch_m = (u16*)(ex + 65536);
    float* cbuf = (float*)(ex + 131072);
    u32* cnt_m  = (u32*)(ex + 262144);
    u32* cnt_h  = (u32*)(ex + 262144 + 64);

    hipFuncSetAttribute((const void*)k_persist,
                        hipFuncAttributeMaxDynamicSharedMemorySize, PERSIST_LDS);

    // zero exchange buffers, c-state, barrier counters (every call -> graph-replay safe)
    hipMemsetAsync(ex, 0, 262144 + 128, stream);

    // weight conversions
    k_cvt<<<512, 256, 0, stream>>>(Wmx[0], Wmxb[0], (long)HD * HD);
    k_cvt<<<512, 256, 0, stream>>>(Wmx[1], Wmxb[1], (long)HD * HD);
    k_cvt<<<512, 256, 0, stream>>>(Wmh[0], Wmhb[0], (long)HD * HD);
    k_cvt<<<512, 256, 0, stream>>>(Wmh[1], Wmhb[1], (long)HD * HD);
    k_cvt<<<1024, 256, 0, stream>>>(Wgx[0], Wgxb[0], (long)G4 * HD);
    k_cvt<<<1024, 256, 0, stream>>>(Wgx[1], Wgxb[1], (long)G4 * HD);
    k_cvt<<<1024, 256, 0, stream>>>(Wgm[0], Wgmb[0], (long)G4 * HD);
    k_cvt<<<1024, 256, 0, stream>>>(Wgm[1], Wgmb[1], (long)G4 * HD);

    for (int l = 0; l < 2; ++l) {
        // A = x @ Wmx^T + bmx for the whole layer (M=16384)
        if (l == 0)
            k_gemm<float><<<dim3(8, 128), 256, 0, stream>>>(inputs, Wmxb[0], bmx[0], Ab, HD);
        else
            k_gemm<u16><<<dim3(8, 128), 256, 0, stream>>>(Yb, Wmxb[1], bmx[1], Ab, HD);
        for (int s = 0; s < NSEG; ++s) {
            // Gx chunk = x @ Wgx^T + bg for 64 steps (M=2048, N=4096)
            if (l == 0)
                k_gemm<float><<<dim3(32, 16), 256, 0, stream>>>(
                    inputs + (long)s * SEG * NB * HD, Wgxb[0], bg[0], Gxb, G4);
            else
                k_gemm<u16><<<dim3(32, 16), 256, 0, stream>>>(
                    Yb + (long)s * SEG * NB * HD, Wgxb[1], bg[1], Gxb, G4);
            k_persist<<<96, 256, PERSIST_LDS, stream>>>(
                Wmhb[l], bmh[l], Wgmb[l], Ab, Gxb,
                exch_h, exch_m, cbuf,
                l ? nullptr : Yb, l ? out : nullptr, out + YSZ,
                l, l * LSEQ + s * SEG, s * SEG, cnt_m, cnt_h);
        }
    }
}

// Round 3
// 18150.089 us; speedup vs baseline: 1.5399x; 1.3511x over previous
//
#include <hip/hip_runtime.h>
#include <hip/hip_bf16.h>

// mLSTM persistent-kernel v3: coherent-exchange (no cache-invalidating fences).
// L=512, N=32, H=1024, 2 layers. Out: ys | hs(2,32,1024) | cs(2,32,1024), fp32.

typedef unsigned short u16;
typedef unsigned int u32;
typedef unsigned long long u64;
typedef __attribute__((ext_vector_type(8))) short bf16x8;
typedef __attribute__((ext_vector_type(4))) float f32x4;

#define LSEQ 512
#define NB   32
#define HD   1024
#define G4   4096
#define YSZ  (LSEQ*NB*HD)
#define NH32 (NB*HD)
#define SEG  64
#define NSEG (LSEQ/SEG)
#define PERSIST_LDS 131072   // Wgm slice only

#define ATOMIC_RLX __ATOMIC_RELAXED
#define SCOPE_AGT __HIP_MEMORY_SCOPE_AGENT

__device__ __forceinline__ float b2f(u16 u) {
    u32 i = ((u32)u) << 16; float f; __builtin_memcpy(&f, &i, 4); return f;
}
__device__ __forceinline__ u16 f2b(float f) {
    u32 x; __builtin_memcpy(&x, &f, 4);
    return (u16)((x + 0x7fffu + ((x >> 16) & 1u)) >> 16);
}
// XOR swizzle: spreads 2KB-stride rows across 16B slots (bank-conflict fix)
__device__ __forceinline__ int SW(int row, int byte) { return byte ^ ((row & 7) << 4); }

// wave-level: wait until *flag >= target (coherent poll, no cache invalidate)
__device__ __forceinline__ void waitflag(u32* flag, u32 target) {
    int lane = threadIdx.x & 63;
    for (;;) {
        u32 t = 0;
        if (lane == 0) t = __hip_atomic_load(flag, ATOMIC_RLX, SCOPE_AGT);
        t = (u32)__shfl((int)t, 0, 64);
        if (t >= target) break;
    }
    asm volatile("" ::: "memory");  // compiler barrier: keep data loads after poll
}
// wave-level: drain this wave's stores to coherence point, then bump flag
__device__ __forceinline__ void signal(u32* flag) {
    asm volatile("s_waitcnt vmcnt(0)" ::: "memory");
    if ((threadIdx.x & 63) == 0)
        __hip_atomic_fetch_add(flag, 1u, ATOMIC_RLX, SCOPE_AGT);
}

// ---------------- f32 -> bf16 conversion ----------------
__global__ void k_cvt(const float* __restrict__ s, u16* __restrict__ d, long n) {
    long i = (long)blockIdx.x * blockDim.x + threadIdx.x;
    long stride = (long)gridDim.x * blockDim.x;
    for (; i < n; i += stride) d[i] = f2b(s[i]);
}

template<typename XT> __device__ __forceinline__ bf16x8 ld8(const XT* p);
template<> __device__ __forceinline__ bf16x8 ld8<u16>(const u16* p) {
    return *(const bf16x8*)p;
}
template<> __device__ __forceinline__ bf16x8 ld8<float>(const float* p) {
    float4 a = *(const float4*)p, b = *(const float4*)(p + 4);
    bf16x8 r;
    r[0]=(short)f2b(a.x); r[1]=(short)f2b(a.y); r[2]=(short)f2b(a.z); r[3]=(short)f2b(a.w);
    r[4]=(short)f2b(b.x); r[5]=(short)f2b(b.y); r[6]=(short)f2b(b.z); r[7]=(short)f2b(b.w);
    return r;
}

// ------- big GEMM: Out[M][ldo] = bf16(X[M][1024] @ W[ncols][1024]^T + bias) -------
template<typename XT>
__global__ __launch_bounds__(256) void k_gemm(
    const XT* __restrict__ X, const u16* __restrict__ W,
    const float* __restrict__ bias, u16* __restrict__ Out, int ldo)
{
    __shared__ u16 As[128][40];
    __shared__ u16 Bs[128][40];
    int bm = blockIdx.y, bn = blockIdx.x;
    int tid = threadIdx.x;
    int w = tid >> 6, lane = tid & 63;
    int wm = w >> 1, wn = w & 1;
    int l16 = lane & 15, lk = lane >> 4;

    f32x4 acc[4][4];
    #pragma unroll
    for (int i = 0; i < 4; ++i)
        #pragma unroll
        for (int j = 0; j < 4; ++j) acc[i][j] = (f32x4){0.f, 0.f, 0.f, 0.f};

    for (int kt = 0; kt < 32; ++kt) {
        __syncthreads();
        #pragma unroll
        for (int c = 0; c < 2; ++c) {
            int cid = tid + c * 256;
            int rrow = cid >> 2, kc = (cid & 3) * 8;
            *(bf16x8*)(&As[rrow][kc]) = ld8<XT>(X + (long)(bm * 128 + rrow) * HD + kt * 32 + kc);
            *(bf16x8*)(&Bs[rrow][kc]) = ld8<u16>(W + (long)(bn * 128 + rrow) * HD + kt * 32 + kc);
        }
        __syncthreads();
        bf16x8 af[4], bfr[4];
        #pragma unroll
        for (int mt = 0; mt < 4; ++mt)
            af[mt] = *(const bf16x8*)(&As[wm * 64 + mt * 16 + l16][lk * 8]);
        #pragma unroll
        for (int nt = 0; nt < 4; ++nt)
            bfr[nt] = *(const bf16x8*)(&Bs[wn * 64 + nt * 16 + l16][lk * 8]);
        #pragma unroll
        for (int mt = 0; mt < 4; ++mt)
            #pragma unroll
            for (int nt = 0; nt < 4; ++nt)
                acc[mt][nt] = __builtin_amdgcn_mfma_f32_16x16x32_bf16(
                    af[mt], bfr[nt], acc[mt][nt], 0, 0, 0);
    }
    #pragma unroll
    for (int mt = 0; mt < 4; ++mt)
        #pragma unroll
        for (int nt = 0; nt < 4; ++nt) {
            int colg = bn * 128 + wn * 64 + nt * 16 + l16;
            float bv = bias[colg];
            #pragma unroll
            for (int r = 0; r < 4; ++r) {
                int rowg = bm * 128 + wm * 64 + mt * 16 + lk * 4 + r;
                Out[(long)rowg * ldo + colg] = f2b(acc[mt][nt][r] + bv);
            }
        }
}

// ---------------- persistent recurrent kernel (one 64-step segment) ----------------
// 64 blocks x 256 thr, 1 block/CU (128KB LDS). Block b owns h/m-cols [16b,16b+16).
// Waves 0,1: gate GEMM + state update (row-tile = wave). Waves 2,3: m GEMM.
__global__ __launch_bounds__(256, 1) void k_persist(
    const u16* __restrict__ Wmhb, const float* __restrict__ bmh,
    const u16* __restrict__ Wgmb,
    const u16* __restrict__ Ab,    // [512][32][1024] layer-local
    const u16* __restrict__ Gxb,   // [SEG][32][4096] chunk-local
    u16* exch_h, u16* exch_m,      // [32][1024] bf16 coherent exchange
    float* __restrict__ cbuf,      // [32][1024] f32 c-state (cross-launch)
    u16* __restrict__ yb, float* __restrict__ yf,
    float* __restrict__ tail,      // out + YSZ
    int l, int tbc, int tbi, u32* cnt_m, u32* cnt_h)
{
    extern __shared__ __align__(16) char lds[];
    const int tid = threadIdx.x;
    const int b = blockIdx.x;
    const int w = tid >> 6, lane = tid & 63;
    const int l16 = lane & 15, lk = lane >> 4;

    // ---- stage Wgm slice (4 gates x 16 cols x 1024 K = 128KB) once, swizzled ----
    for (int it = 0; it < 32; ++it) {
        int cch = tid + it * 256;            // 0..8191 16B-chunks
        int lr = cch >> 7, k8 = cch & 127;   // lr: 0..63 = gate*16 + col16
        int g = lr >> 4, c16 = lr & 15;
        bf16x8 v = *(const bf16x8*)(Wgmb + (long)(g * 1024 + 16 * b + c16) * HD + k8 * 8);
        *(bf16x8*)(lds + SW(lr, lr * 2048 + k8 * 16)) = v;
    }
    __syncthreads();

    if (w >= 2) {
        // ================= phase 1: m = A_t * (h @ Wmh^T + bmh) =================
        const int rt = w - 2;                 // batch row-tile
        const int colg = 16 * b + l16;        // m-col
        bf16x8 wmh[32];                       // Wmh B-frags, register-resident
        #pragma unroll
        for (int kt = 0; kt < 32; ++kt)
            wmh[kt] = *(const bf16x8*)(Wmhb + (long)colg * HD + kt * 32 + lk * 8);
        const float bcol = bmh[colg];
        const u64* hrow = (const u64*)exch_h + (rt * 16 + l16) * (HD / 4);
        u16* mdst = exch_m + (rt * 16 + lk * 4) * HD + colg;

        for (int t = 0; t < SEG; ++t) {
            const u32 gt = (u32)(tbc + t);
            const u16* At = Ab + (long)(tbi + t) * NH32;
            u16 atv[4];
            #pragma unroll
            for (int r = 0; r < 4; ++r)
                atv[r] = At[(rt * 16 + lk * 4 + r) * HD + colg];
            waitflag(cnt_h, 128u * gt);
            f32x4 acc = (f32x4){0.f, 0.f, 0.f, 0.f};
            #pragma unroll
            for (int g2 = 0; g2 < 4; ++g2) {
                u64 hq[16];
                #pragma unroll
                for (int i = 0; i < 8; ++i) {
                    int kt = g2 * 8 + i;
                    hq[2*i]   = __hip_atomic_load(hrow + kt * 8 + lk * 2,     ATOMIC_RLX, SCOPE_AGT);
                    hq[2*i+1] = __hip_atomic_load(hrow + kt * 8 + lk * 2 + 1, ATOMIC_RLX, SCOPE_AGT);
                }
                #pragma unroll
                for (int i = 0; i < 8; ++i) {
                    union { bf16x8 v; u64 q[2]; } u;
                    u.q[0] = hq[2*i]; u.q[1] = hq[2*i+1];
                    acc = __builtin_amdgcn_mfma_f32_16x16x32_bf16(u.v, wmh[g2*8+i], acc, 0, 0, 0);
                }
            }
            #pragma unroll
            for (int r = 0; r < 4; ++r)
                __hip_atomic_store(mdst + r * HD,
                    f2b(b2f(atv[r]) * (acc[r] + bcol)), ATOMIC_RLX, SCOPE_AGT);
            signal(cnt_m);
        }
    } else {
        // ===== phase 2: g = Gx_t + m @ Wgm^T; gates; h,c (all 4 gates per lane) =====
        const int rt = w;
        const int hc = 16 * b + l16;
        f32x4 creg;
        #pragma unroll
        for (int r = 0; r < 4; ++r)
            creg[r] = cbuf[(rt * 16 + lk * 4 + r) * HD + hc];
        const u64* mrow = (const u64*)exch_m + (rt * 16 + l16) * (HD / 4);

        for (int t = 0; t < SEG; ++t) {
            const u32 gt = (u32)(tbc + t);
            const u16* Gx = Gxb + (long)t * NB * G4;
            u16 gxv[4][4];
            #pragma unroll
            for (int g = 0; g < 4; ++g)
                #pragma unroll
                for (int r = 0; r < 4; ++r)
                    gxv[g][r] = Gx[(long)(rt * 16 + lk * 4 + r) * G4 + g * 1024 + hc];
            waitflag(cnt_m, 128u * (gt + 1));
            f32x4 acc[4];
            #pragma unroll
            for (int g = 0; g < 4; ++g) acc[g] = (f32x4){0.f, 0.f, 0.f, 0.f};
            #pragma unroll
            for (int g2 = 0; g2 < 4; ++g2) {
                u64 mq[16];
                #pragma unroll
                for (int i = 0; i < 8; ++i) {
                    int kt = g2 * 8 + i;
                    mq[2*i]   = __hip_atomic_load(mrow + kt * 8 + lk * 2,     ATOMIC_RLX, SCOPE_AGT);
                    mq[2*i+1] = __hip_atomic_load(mrow + kt * 8 + lk * 2 + 1, ATOMIC_RLX, SCOPE_AGT);
                }
                #pragma unroll
                for (int i = 0; i < 8; ++i) {
                    int kt = g2 * 8 + i;
                    union { bf16x8 v; u64 q[2]; } u;
                    u.q[0] = mq[2*i]; u.q[1] = mq[2*i+1];
                    #pragma unroll
                    for (int g = 0; g < 4; ++g) {
                        int lr = g * 16 + l16;
                        bf16x8 bfrag = *(const bf16x8*)(lds + SW(lr, lr * 2048 + kt * 64 + lk * 16));
                        acc[g] = __builtin_amdgcn_mfma_f32_16x16x32_bf16(u.v, bfrag, acc[g], 0, 0, 0);
                    }
                }
            }
            #pragma unroll
            for (int r = 0; r < 4; ++r) {
                int row = rt * 16 + lk * 4 + r;
                float ig = acc[0][r] + b2f(gxv[0][r]);
                float fg = acc[1][r] + b2f(gxv[1][r]);
                float zg = acc[2][r] + b2f(gxv[2][r]);
                float og = acc[3][r] + b2f(gxv[3][r]);
                float si = 1.f / (1.f + expf(-ig));
                float sf = 1.f / (1.f + expf(-fg));
                float so = 1.f / (1.f + expf(-og));
                float cn = sf * creg[r] + si * tanhf(zg);
                float hn = so * tanhf(cn);
                creg[r] = cn;
                __hip_atomic_store(exch_h + (long)row * HD + hc, f2b(hn), ATOMIC_RLX, SCOPE_AGT);
                long yidx = (long)(tbi + t) * NH32 + (long)row * HD + hc;
                if (yb) yb[yidx] = f2b(hn); else yf[yidx] = hn;
                if (tbi + t == LSEQ - 1) {
                    tail[(long)l * NH32 + row * HD + hc] = hn;
                    tail[2L * NH32 + (long)l * NH32 + row * HD + hc] = cn;
                }
            }
            signal(cnt_h);
        }
        #pragma unroll
        for (int r = 0; r < 4; ++r)
            cbuf[(rt * 16 + lk * 4 + r) * HD + hc] = creg[r];
    }
}

extern "C" void kernel_launch(void* const* d_in, const int* in_sizes, int n_in,
                              void* d_out, int out_size, void* d_ws, size_t ws_size,
                              hipStream_t stream) {
    (void)in_sizes; (void)n_in; (void)out_size; (void)ws_size;
    const float* inputs = (const float*)d_in[0];
    const float* Wmx[2] = {(const float*)d_in[1], (const float*)d_in[8]};
    const float* Wmh[2] = {(const float*)d_in[2], (const float*)d_in[9]};
    const float* bmx[2] = {(const float*)d_in[3], (const float*)d_in[10]};
    const float* bmh[2] = {(const float*)d_in[4], (const float*)d_in[11]};
    const float* Wgx[2] = {(const float*)d_in[5], (const float*)d_in[12]};
    const float* Wgm[2] = {(const float*)d_in[6], (const float*)d_in[13]};
    const float* bg[2]  = {(const float*)d_in[7], (const float*)d_in[14]};
    float* out = (float*)d_out;

    char* ws = (char*)d_ws;
    const long MB = 1024L * 1024L;
    u16* Wmxb[2] = {(u16*)(ws + 0 * MB),  (u16*)(ws + 2 * MB)};
    u16* Wmhb[2] = {(u16*)(ws + 4 * MB),  (u16*)(ws + 6 * MB)};
    u16* Wgxb[2] = {(u16*)(ws + 8 * MB),  (u16*)(ws + 16 * MB)};
    u16* Wgmb[2] = {(u16*)(ws + 24 * MB), (u16*)(ws + 32 * MB)};
    u16* Yb  = (u16*)(ws + 40 * MB);   // 32MB bf16 layer-0 outputs
    u16* Ab  = (u16*)(ws + 72 * MB);   // 32MB bf16 A = x@Wmx+bmx
    u16* Gxb = (u16*)(ws + 104 * MB);  // 16MB bf16 Gx chunk
    char* ex = ws + 120 * MB;
    u16* exch_h = (u16*)ex;                       // 64KB
    u16* exch_m = (u16*)(ex + 65536);             // 64KB
    float* cbuf = (float*)(ex + 131072);          // 128KB
    u32* cnt_m  = (u32*)(ex + 262144);            // own 4KB page
    u32* cnt_h  = (u32*)(ex + 262144 + 4096);     // own 4KB page

    hipFuncSetAttribute((const void*)k_persist,
                        hipFuncAttributeMaxDynamicSharedMemorySize, PERSIST_LDS);

    // zero exchange + c + counters each call (graph-replay deterministic)
    hipMemsetAsync(ex, 0, 262144 + 8192, stream);

    k_cvt<<<512, 256, 0, stream>>>(Wmx[0], Wmxb[0], (long)HD * HD);
    k_cvt<<<512, 256, 0, stream>>>(Wmx[1], Wmxb[1], (long)HD * HD);
    k_cvt<<<512, 256, 0, stream>>>(Wmh[0], Wmhb[0], (long)HD * HD);
    k_cvt<<<512, 256, 0, stream>>>(Wmh[1], Wmhb[1], (long)HD * HD);
    k_cvt<<<1024, 256, 0, stream>>>(Wgx[0], Wgxb[0], (long)G4 * HD);
    k_cvt<<<1024, 256, 0, stream>>>(Wgx[1], Wgxb[1], (long)G4 * HD);
    k_cvt<<<1024, 256, 0, stream>>>(Wgm[0], Wgmb[0], (long)G4 * HD);
    k_cvt<<<1024, 256, 0, stream>>>(Wgm[1], Wgmb[1], (long)G4 * HD);

    for (int l = 0; l < 2; ++l) {
        if (l == 0)
            k_gemm<float><<<dim3(8, 128), 256, 0, stream>>>(inputs, Wmxb[0], bmx[0], Ab, HD);
        else
            k_gemm<u16><<<dim3(8, 128), 256, 0, stream>>>(Yb, Wmxb[1], bmx[1], Ab, HD);
        for (int s = 0; s < NSEG; ++s) {
            if (l == 0)
                k_gemm<float><<<dim3(32, 16), 256, 0, stream>>>(
                    inputs + (long)s * SEG * NB * HD, Wgxb[0], bg[0], Gxb, G4);
            else
                k_gemm<u16><<<dim3(32, 16), 256, 0, stream>>>(
                    Yb + (long)s * SEG * NB * HD, Wgxb[1], bg[1], Gxb, G4);
            k_persist<<<64, 256, PERSIST_LDS, stream>>>(
                Wmhb[l], bmh[l], Wgmb[l], Ab, Gxb,
                exch_h, exch_m, cbuf,
                l ? nullptr : Yb, l ? out : nullptr, out + YSZ,
                l, l * LSEQ + s * SEG, s * SEG, cnt_m, cnt_h);
        }
    }
}

// Round 4
// 15470.105 us; speedup vs baseline: 1.8067x; 1.1732x over previous
//
#include <hip/hip_runtime.h>
#include <hip/hip_bf16.h>

// mLSTM persistent-kernel v4: per-wave flag slots (no contended RMW barriers).
// L=512, N=32, H=1024, 2 layers. Out: ys | hs(2,32,1024) | cs(2,32,1024), fp32.

typedef unsigned short u16;
typedef unsigned int u32;
typedef unsigned long long u64;
typedef __attribute__((ext_vector_type(8))) short bf16x8;
typedef __attribute__((ext_vector_type(4))) float f32x4;

#define LSEQ 512
#define NB   32
#define HD   1024
#define G4   4096
#define YSZ  (LSEQ*NB*HD)
#define NH32 (NB*HD)
#define SEG  64
#define NSEG (LSEQ/SEG)
#define PERSIST_LDS 131072   // Wgm slice only

#define ATOMIC_RLX __ATOMIC_RELAXED
#define SCOPE_AGT __HIP_MEMORY_SCOPE_AGENT

__device__ __forceinline__ float b2f(u16 u) {
    u32 i = ((u32)u) << 16; float f; __builtin_memcpy(&f, &i, 4); return f;
}
__device__ __forceinline__ u16 f2b(float f) {
    u32 x; __builtin_memcpy(&x, &f, 4);
    return (u16)((x + 0x7fffu + ((x >> 16) & 1u)) >> 16);
}
// XOR swizzle: spreads 2KB-stride rows across 16B slots (bank-conflict fix)
__device__ __forceinline__ int SW(int row, int byte) { return byte ^ ((row & 7) << 4); }

// Wait until every block's two wave-slots reach >= target.
// Lane b gathers block b's 8B slot-pair (coherent load); no RMW anywhere.
__device__ __forceinline__ void waitpair(const u32* flags, u32 target) {
    const int lane = threadIdx.x & 63;
    const u64* p = (const u64*)flags + (size_t)lane * 16;  // 128B line per block
    for (;;) {
        u64 v = __hip_atomic_load(p, ATOMIC_RLX, SCOPE_AGT);
        u32 lo = (u32)v, hi = (u32)(v >> 32);
        if (__all(lo >= target && hi >= target)) break;
    }
    asm volatile("" ::: "memory");  // keep data loads after the poll
}
// Drain this wave's write-through stores, then publish step number in own slot.
__device__ __forceinline__ void signal_slot(u32* flags, int b, int rt, u32 val) {
    asm volatile("s_waitcnt vmcnt(0)" ::: "memory");
    if ((threadIdx.x & 63) == 0)
        __hip_atomic_store(flags + b * 32 + rt, val, ATOMIC_RLX, SCOPE_AGT);
}

// ---------------- f32 -> bf16 conversion ----------------
__global__ void k_cvt(const float* __restrict__ s, u16* __restrict__ d, long n) {
    long i = (long)blockIdx.x * blockDim.x + threadIdx.x;
    long stride = (long)gridDim.x * blockDim.x;
    for (; i < n; i += stride) d[i] = f2b(s[i]);
}

template<typename XT> __device__ __forceinline__ bf16x8 ld8(const XT* p);
template<> __device__ __forceinline__ bf16x8 ld8<u16>(const u16* p) {
    return *(const bf16x8*)p;
}
template<> __device__ __forceinline__ bf16x8 ld8<float>(const float* p) {
    float4 a = *(const float4*)p, b = *(const float4*)(p + 4);
    bf16x8 r;
    r[0]=(short)f2b(a.x); r[1]=(short)f2b(a.y); r[2]=(short)f2b(a.z); r[3]=(short)f2b(a.w);
    r[4]=(short)f2b(b.x); r[5]=(short)f2b(b.y); r[6]=(short)f2b(b.z); r[7]=(short)f2b(b.w);
    return r;
}

// ------- big GEMM: Out[M][ldo] = bf16(X[M][1024] @ W[ncols][1024]^T + bias) -------
template<typename XT>
__global__ __launch_bounds__(256) void k_gemm(
    const XT* __restrict__ X, const u16* __restrict__ W,
    const float* __restrict__ bias, u16* __restrict__ Out, int ldo)
{
    __shared__ u16 As[128][40];
    __shared__ u16 Bs[128][40];
    int bm = blockIdx.y, bn = blockIdx.x;
    int tid = threadIdx.x;
    int w = tid >> 6, lane = tid & 63;
    int wm = w >> 1, wn = w & 1;
    int l16 = lane & 15, lk = lane >> 4;

    f32x4 acc[4][4];
    #pragma unroll
    for (int i = 0; i < 4; ++i)
        #pragma unroll
        for (int j = 0; j < 4; ++j) acc[i][j] = (f32x4){0.f, 0.f, 0.f, 0.f};

    for (int kt = 0; kt < 32; ++kt) {
        __syncthreads();
        #pragma unroll
        for (int c = 0; c < 2; ++c) {
            int cid = tid + c * 256;
            int rrow = cid >> 2, kc = (cid & 3) * 8;
            *(bf16x8*)(&As[rrow][kc]) = ld8<XT>(X + (long)(bm * 128 + rrow) * HD + kt * 32 + kc);
            *(bf16x8*)(&Bs[rrow][kc]) = ld8<u16>(W + (long)(bn * 128 + rrow) * HD + kt * 32 + kc);
        }
        __syncthreads();
        bf16x8 af[4], bfr[4];
        #pragma unroll
        for (int mt = 0; mt < 4; ++mt)
            af[mt] = *(const bf16x8*)(&As[wm * 64 + mt * 16 + l16][lk * 8]);
        #pragma unroll
        for (int nt = 0; nt < 4; ++nt)
            bfr[nt] = *(const bf16x8*)(&Bs[wn * 64 + nt * 16 + l16][lk * 8]);
        #pragma unroll
        for (int mt = 0; mt < 4; ++mt)
            #pragma unroll
            for (int nt = 0; nt < 4; ++nt)
                acc[mt][nt] = __builtin_amdgcn_mfma_f32_16x16x32_bf16(
                    af[mt], bfr[nt], acc[mt][nt], 0, 0, 0);
    }
    #pragma unroll
    for (int mt = 0; mt < 4; ++mt)
        #pragma unroll
        for (int nt = 0; nt < 4; ++nt) {
            int colg = bn * 128 + wn * 64 + nt * 16 + l16;
            float bv = bias[colg];
            #pragma unroll
            for (int r = 0; r < 4; ++r) {
                int rowg = bm * 128 + wm * 64 + mt * 16 + lk * 4 + r;
                Out[(long)rowg * ldo + colg] = f2b(acc[mt][nt][r] + bv);
            }
        }
}

// ---------------- persistent recurrent kernel (one 64-step segment) ----------------
// 64 blocks x 256 thr, 1 block/CU (128KB LDS). Block b owns h/m-cols [16b,16b+16).
// Waves 0,1: gate GEMM + state update (row-tile = wave). Waves 2,3: m GEMM.
__global__ __launch_bounds__(256, 1) void k_persist(
    const u16* __restrict__ Wmhb, const float* __restrict__ bmh,
    const u16* __restrict__ Wgmb,
    const u16* __restrict__ Ab,    // [512][32][1024] layer-local
    const u16* __restrict__ Gxb,   // [SEG][32][4096] chunk-local
    u16* exch_h, u16* exch_m,      // [32][1024] bf16 coherent exchange
    float* __restrict__ cbuf,      // [32][1024] f32 c-state (cross-launch)
    u16* __restrict__ yb, float* __restrict__ yf,
    float* __restrict__ tail,      // out + YSZ
    int l, int tbc, int tbi, u32* flagM, u32* flagH)
{
    extern __shared__ __align__(16) char lds[];
    const int tid = threadIdx.x;
    const int b = blockIdx.x;
    const int w = tid >> 6, lane = tid & 63;
    const int l16 = lane & 15, lk = lane >> 4;

    // ---- stage Wgm slice (4 gates x 16 cols x 1024 K = 128KB) once, swizzled ----
    for (int it = 0; it < 32; ++it) {
        int cch = tid + it * 256;            // 0..8191 16B-chunks
        int lr = cch >> 7, k8 = cch & 127;   // lr: 0..63 = gate*16 + col16
        int g = lr >> 4, c16 = lr & 15;
        bf16x8 v = *(const bf16x8*)(Wgmb + (long)(g * 1024 + 16 * b + c16) * HD + k8 * 8);
        *(bf16x8*)(lds + SW(lr, lr * 2048 + k8 * 16)) = v;
    }
    __syncthreads();

    if (w >= 2) {
        // ================= phase 1: m = A_t * (h @ Wmh^T + bmh) =================
        const int rt = w - 2;                 // batch row-tile
        const int colg = 16 * b + l16;        // m-col
        bf16x8 wmh[32];                       // Wmh B-frags, register-resident
        #pragma unroll
        for (int kt = 0; kt < 32; ++kt)
            wmh[kt] = *(const bf16x8*)(Wmhb + (long)colg * HD + kt * 32 + lk * 8);
        const float bcol = bmh[colg];
        const u64* hrow = (const u64*)exch_h + (rt * 16 + l16) * (HD / 4);
        u16* mdst = exch_m + (rt * 16 + lk * 4) * HD + colg;

        for (int t = 0; t < SEG; ++t) {
            const u32 gt = (u32)(tbc + t);
            const u16* At = Ab + (long)(tbi + t) * NH32;
            u16 atv[4];
            #pragma unroll
            for (int r = 0; r < 4; ++r)
                atv[r] = At[(rt * 16 + lk * 4 + r) * HD + colg];
            waitpair(flagH, gt);              // h_{t-1} published by all blocks
            f32x4 acc = (f32x4){0.f, 0.f, 0.f, 0.f};
            #pragma unroll
            for (int g2 = 0; g2 < 4; ++g2) {
                u64 hq[16];
                #pragma unroll
                for (int i = 0; i < 8; ++i) {
                    int kt = g2 * 8 + i;
                    hq[2*i]   = __hip_atomic_load(hrow + kt * 8 + lk * 2,     ATOMIC_RLX, SCOPE_AGT);
                    hq[2*i+1] = __hip_atomic_load(hrow + kt * 8 + lk * 2 + 1, ATOMIC_RLX, SCOPE_AGT);
                }
                #pragma unroll
                for (int i = 0; i < 8; ++i) {
                    union { bf16x8 v; u64 q[2]; } u;
                    u.q[0] = hq[2*i]; u.q[1] = hq[2*i+1];
                    acc = __builtin_amdgcn_mfma_f32_16x16x32_bf16(u.v, wmh[g2*8+i], acc, 0, 0, 0);
                }
            }
            #pragma unroll
            for (int r = 0; r < 4; ++r)
                __hip_atomic_store(mdst + r * HD,
                    f2b(b2f(atv[r]) * (acc[r] + bcol)), ATOMIC_RLX, SCOPE_AGT);
            signal_slot(flagM, b, rt, gt + 1);   // m_t from this wave is visible
        }
    } else {
        // ===== phase 2: g = Gx_t + m @ Wgm^T; gates; h,c (all 4 gates per lane) =====
        const int rt = w;
        const int hc = 16 * b + l16;
        f32x4 creg;
        #pragma unroll
        for (int r = 0; r < 4; ++r)
            creg[r] = cbuf[(rt * 16 + lk * 4 + r) * HD + hc];
        const u64* mrow = (const u64*)exch_m + (rt * 16 + l16) * (HD / 4);

        for (int t = 0; t < SEG; ++t) {
            const u32 gt = (u32)(tbc + t);
            const u16* Gx = Gxb + (long)t * NB * G4;
            u16 gxv[4][4];
            #pragma unroll
            for (int g = 0; g < 4; ++g)
                #pragma unroll
                for (int r = 0; r < 4; ++r)
                    gxv[g][r] = Gx[(long)(rt * 16 + lk * 4 + r) * G4 + g * 1024 + hc];
            waitpair(flagM, gt + 1);          // m_t published by all blocks
            f32x4 acc[4];
            #pragma unroll
            for (int g = 0; g < 4; ++g) acc[g] = (f32x4){0.f, 0.f, 0.f, 0.f};
            #pragma unroll
            for (int g2 = 0; g2 < 4; ++g2) {
                u64 mq[16];
                #pragma unroll
                for (int i = 0; i < 8; ++i) {
                    int kt = g2 * 8 + i;
                    mq[2*i]   = __hip_atomic_load(mrow + kt * 8 + lk * 2,     ATOMIC_RLX, SCOPE_AGT);
                    mq[2*i+1] = __hip_atomic_load(mrow + kt * 8 + lk * 2 + 1, ATOMIC_RLX, SCOPE_AGT);
                }
                #pragma unroll
                for (int i = 0; i < 8; ++i) {
                    int kt = g2 * 8 + i;
                    union { bf16x8 v; u64 q[2]; } u;
                    u.q[0] = mq[2*i]; u.q[1] = mq[2*i+1];
                    #pragma unroll
                    for (int g = 0; g < 4; ++g) {
                        int lr = g * 16 + l16;
                        bf16x8 bfrag = *(const bf16x8*)(lds + SW(lr, lr * 2048 + kt * 64 + lk * 16));
                        acc[g] = __builtin_amdgcn_mfma_f32_16x16x32_bf16(u.v, bfrag, acc[g], 0, 0, 0);
                    }
                }
            }
            #pragma unroll
            for (int r = 0; r < 4; ++r) {
                int row = rt * 16 + lk * 4 + r;
                float ig = acc[0][r] + b2f(gxv[0][r]);
                float fg = acc[1][r] + b2f(gxv[1][r]);
                float zg = acc[2][r] + b2f(gxv[2][r]);
                float og = acc[3][r] + b2f(gxv[3][r]);
                float si = 1.f / (1.f + expf(-ig));
                float sf = 1.f / (1.f + expf(-fg));
                float so = 1.f / (1.f + expf(-og));
                float cn = sf * creg[r] + si * tanhf(zg);
                float hn = so * tanhf(cn);
                creg[r] = cn;
                __hip_atomic_store(exch_h + (long)row * HD + hc, f2b(hn), ATOMIC_RLX, SCOPE_AGT);
                long yidx = (long)(tbi + t) * NH32 + (long)row * HD + hc;
                if (yb) yb[yidx] = f2b(hn); else yf[yidx] = hn;
                if (tbi + t == LSEQ - 1) {
                    tail[(long)l * NH32 + row * HD + hc] = hn;
                    tail[2L * NH32 + (long)l * NH32 + row * HD + hc] = cn;
                }
            }
            signal_slot(flagH, b, rt, gt + 1);   // h_t from this wave is visible
        }
        #pragma unroll
        for (int r = 0; r < 4; ++r)
            cbuf[(rt * 16 + lk * 4 + r) * HD + hc] = creg[r];
    }
}

extern "C" void kernel_launch(void* const* d_in, const int* in_sizes, int n_in,
                              void* d_out, int out_size, void* d_ws, size_t ws_size,
                              hipStream_t stream) {
    (void)in_sizes; (void)n_in; (void)out_size; (void)ws_size;
    const float* inputs = (const float*)d_in[0];
    const float* Wmx[2] = {(const float*)d_in[1], (const float*)d_in[8]};
    const float* Wmh[2] = {(const float*)d_in[2], (const float*)d_in[9]};
    const float* bmx[2] = {(const float*)d_in[3], (const float*)d_in[10]};
    const float* bmh[2] = {(const float*)d_in[4], (const float*)d_in[11]};
    const float* Wgx[2] = {(const float*)d_in[5], (const float*)d_in[12]};
    const float* Wgm[2] = {(const float*)d_in[6], (const float*)d_in[13]};
    const float* bg[2]  = {(const float*)d_in[7], (const float*)d_in[14]};
    float* out = (float*)d_out;

    char* ws = (char*)d_ws;
    const long MB = 1024L * 1024L;
    u16* Wmxb[2] = {(u16*)(ws + 0 * MB),  (u16*)(ws + 2 * MB)};
    u16* Wmhb[2] = {(u16*)(ws + 4 * MB),  (u16*)(ws + 6 * MB)};
    u16* Wgxb[2] = {(u16*)(ws + 8 * MB),  (u16*)(ws + 16 * MB)};
    u16* Wgmb[2] = {(u16*)(ws + 24 * MB), (u16*)(ws + 32 * MB)};
    u16* Yb  = (u16*)(ws + 40 * MB);   // 32MB bf16 layer-0 outputs
    u16* Ab  = (u16*)(ws + 72 * MB);   // 32MB bf16 A = x@Wmx+bmx
    u16* Gxb = (u16*)(ws + 104 * MB);  // 16MB bf16 Gx chunk
    char* ex = ws + 120 * MB;
    u16* exch_h = (u16*)ex;                       // 64KB
    u16* exch_m = (u16*)(ex + 65536);             // 64KB
    float* cbuf = (float*)(ex + 131072);          // 128KB
    u32* flagM  = (u32*)(ex + 262144);            // 64 x 128B slot lines
    u32* flagH  = (u32*)(ex + 262144 + 8192);     // 64 x 128B slot lines

    hipFuncSetAttribute((const void*)k_persist,
                        hipFuncAttributeMaxDynamicSharedMemorySize, PERSIST_LDS);

    // zero exchange + c + flags each call (graph-replay deterministic)
    hipMemsetAsync(ex, 0, 262144 + 16384, stream);

    k_cvt<<<512, 256, 0, stream>>>(Wmx[0], Wmxb[0], (long)HD * HD);
    k_cvt<<<512, 256, 0, stream>>>(Wmx[1], Wmxb[1], (long)HD * HD);
    k_cvt<<<512, 256, 0, stream>>>(Wmh[0], Wmhb[0], (long)HD * HD);
    k_cvt<<<512, 256, 0, stream>>>(Wmh[1], Wmhb[1], (long)HD * HD);
    k_cvt<<<1024, 256, 0, stream>>>(Wgx[0], Wgxb[0], (long)G4 * HD);
    k_cvt<<<1024, 256, 0, stream>>>(Wgx[1], Wgxb[1], (long)G4 * HD);
    k_cvt<<<1024, 256, 0, stream>>>(Wgm[0], Wgmb[0], (long)G4 * HD);
    k_cvt<<<1024, 256, 0, stream>>>(Wgm[1], Wgmb[1], (long)G4 * HD);

    for (int l = 0; l < 2; ++l) {
        if (l == 0)
            k_gemm<float><<<dim3(8, 128), 256, 0, stream>>>(inputs, Wmxb[0], bmx[0], Ab, HD);
        else
            k_gemm<u16><<<dim3(8, 128), 256, 0, stream>>>(Yb, Wmxb[1], bmx[1], Ab, HD);
        for (int s = 0; s < NSEG; ++s) {
            if (l == 0)
                k_gemm<float><<<dim3(32, 16), 256, 0, stream>>>(
                    inputs + (long)s * SEG * NB * HD, Wgxb[0], bg[0], Gxb, G4);
            else
                k_gemm<u16><<<dim3(32, 16), 256, 0, stream>>>(
                    Yb + (long)s * SEG * NB * HD, Wgxb[1], bg[1], Gxb, G4);
            k_persist<<<64, 256, PERSIST_LDS, stream>>>(
                Wmhb[l], bmh[l], Wgmb[l], Ab, Gxb,
                exch_h, exch_m, cbuf,
                l ? nullptr : Yb, l ? out : nullptr, out + YSZ,
                l, l * LSEQ + s * SEG, s * SEG, flagM, flagH);
        }
    }
}